// Round 14
// baseline (668.812 us; speedup 1.0000x reference)
//
#include <hip/hip_runtime.h>
#include <cstdint>

// SplineConv MeshEncoder: 3 layers, K=3 DIM=3 M=27, dims 3->64->64->64.
// R14 = R13 with layer64 Phase A FORCED-SCALAR edge chain:
//  - rs/re readfirstlane'd -> e provably SGPR,
//  - batch metas via ONE coalesced lane-load + v_readlane (src/base -> SGPR),
//  - gathers saddr-form, weights s_load_dwordx8 consumed as SGPR operands.
// Rationale: measured ~300 VALU cyc/edge vs ~20 modeled -> compiler was
// emitting per-lane vector loads + 64b addressing for meta/weight loads.
// layer0 / preproc / Phase B unchanged (controls).

typedef __attribute__((ext_vector_type(8))) short short8;
typedef __attribute__((ext_vector_type(4))) float floatx4;

__device__ inline short f2bf(float f) {
    union { float f; unsigned u; } x; x.f = f;
    unsigned r = x.u + 0x7FFF + ((x.u >> 16) & 1);   // round-to-nearest-even
    return (short)(r >> 16);
}

// ---------------- preprocessing (R10-proven) ----------------

__global__ void count_kernel(const int* __restrict__ ei, int* __restrict__ count, int E) {
    int e = blockIdx.x * blockDim.x + threadIdx.x;
    if (e < E) atomicAdd(&count[ei[E + e]], 1);
}

__global__ __launch_bounds__(1024) void scan_tile_kernel(const int* __restrict__ count,
                                                         int* __restrict__ row_ptr,
                                                         int* __restrict__ bsum, int N) {
    __shared__ int wsum[16];
    int tid = threadIdx.x, lane = tid & 63, wid = tid >> 6;
    int i = blockIdx.x * 1024 + tid;
    int v = (i < N) ? count[i] : 0;
    int incl = v;
#pragma unroll
    for (int off = 1; off < 64; off <<= 1) {
        int t = __shfl_up(incl, off, 64);
        if (lane >= off) incl += t;
    }
    if (lane == 63) wsum[wid] = incl;
    __syncthreads();
    if (tid < 16) {
        int w = wsum[tid];
#pragma unroll
        for (int off = 1; off < 16; off <<= 1) {
            int t = __shfl_up(w, off, 16);
            if ((tid & 15) >= off) w += t;
        }
        wsum[tid] = w;
    }
    __syncthreads();
    int waveoff = (wid > 0) ? wsum[wid - 1] : 0;
    if (i < N) row_ptr[i] = waveoff + incl - v;
    if (tid == 1023) bsum[blockIdx.x] = waveoff + incl;
}

__global__ __launch_bounds__(64) void scan_bsum_kernel(const int* __restrict__ bsum,
                                                       int* __restrict__ boff,
                                                       int* __restrict__ tot, int nb) {
    int tid = threadIdx.x;
    int v = (tid < nb) ? bsum[tid] : 0;
    int incl = v;
#pragma unroll
    for (int off = 1; off < 64; off <<= 1) {
        int t = __shfl_up(incl, off, 64);
        if (tid >= off) incl += t;
    }
    boff[tid] = incl - v;
    if (tid == 63) tot[0] = incl;
}

__global__ __launch_bounds__(1024) void scan_add_kernel(int* __restrict__ row_ptr,
                                                        const int* __restrict__ boff,
                                                        const int* __restrict__ tot,
                                                        int* __restrict__ cursor, int N) {
    int i = blockIdx.x * 1024 + threadIdx.x;
    if (i < N) {
        int r = row_ptr[i] + boff[blockIdx.x];
        row_ptr[i] = r;
        cursor[i] = r;
    }
    if (i == 0) row_ptr[N] = tot[0];
}

// Per edge: meta = src | base<<24, weights pre-scaled by 1/deg, scattered to
// dst-sorted position (two float4 stores). kidx = base + {0,1,3,4,9,10,12,13}[c].
__global__ void basis_sort_kernel(const int* __restrict__ ei, const float* __restrict__ attr,
                                  const int* __restrict__ count, int* __restrict__ cursor,
                                  int* __restrict__ s_meta, float* __restrict__ s_w, int E) {
    int e = blockIdx.x * blockDim.x + threadIdx.x;
    if (e >= E) return;
    int src = ei[e];
    int dst = ei[E + e];
    float f[3]; int i0[3];
#pragma unroll
    for (int d = 0; d < 3; d++) {
        float pos = attr[e * 3 + d] * 2.0f;          // K-1 = 2
        float fl = floorf(pos);
        fl = fminf(fmaxf(fl, 0.0f), 1.0f);           // clip to [0, K-2]
        i0[d] = (int)fl;
        f[d] = pos - fl;
    }
    int base = i0[0] + 3 * i0[1] + 9 * i0[2];        // in {0,1,3,4,9,10,12,13}
    float invd = 1.0f / fmaxf((float)count[dst], 1.0f);
    int p = atomicAdd(&cursor[dst], 1);
    s_meta[p] = src | (base << 24);
    float w[8];
#pragma unroll
    for (int c = 0; c < 8; c++) {
        float ww = 1.0f;
#pragma unroll
        for (int d = 0; d < 3; d++) {
            int off = (c >> d) & 1;
            ww *= off ? f[d] : (1.0f - f[d]);
        }
        w[c] = ww * invd;
    }
    floatx4 w03 = {w[0], w[1], w[2], w[3]};
    floatx4 w47 = {w[4], w[5], w[6], w[7]};
    *(floatx4*)(s_w + (size_t)p * 8) = w03;
    *(floatx4*)(s_w + (size_t)p * 8 + 4) = w47;
}

// Pre-swizzle [W(1728,64); Wr(64,64)] into bf16 MFMA B-frag order (R1-proven).
__global__ void build_wb2(const float* __restrict__ Wa, const float* __restrict__ Ra,
                          unsigned short* __restrict__ wba,
                          const float* __restrict__ Wb, const float* __restrict__ Rb,
                          unsigned short* __restrict__ wbb) {
    int idx0 = blockIdx.x * blockDim.x + threadIdx.x;   // [0, 2*4*56*64)
    int half = idx0 / (4 * 56 * 64);
    if (half >= 2) return;
    int idx = idx0 - half * (4 * 56 * 64);
    const float* W = half ? Wb : Wa;
    const float* Wr = half ? Rb : Ra;
    unsigned short* wb = half ? wbb : wba;
    int l = idx & 63;
    int c = (idx >> 6) % 56;
    int t = idx / (56 * 64);
    int q = l >> 4, o = t * 16 + (l & 15);
    short8 out;
#pragma unroll
    for (int j = 0; j < 8; j++) {
        int k = c * 32 + q * 8 + j;
        float v = (k < 1728) ? W[(size_t)k * 64 + o] : Wr[(size_t)(k - 1728) * 64 + o];
        out[j] = f2bf(v);
    }
    *(short8*)(wb + (size_t)idx * 8) = out;
}

// ---------------- layer 0 (CIN=3): dual-edge Phase A (R13-proven) ----------------
__global__ __launch_bounds__(256) void layer0_kernel(
    const float* __restrict__ x, const float* __restrict__ W0,
    const float* __restrict__ Wr, const float* __restrict__ bias,
    const int* __restrict__ row_ptr, const int* __restrict__ s_meta,
    const float* __restrict__ s_w, float* __restrict__ h_out, int N) {
    constexpr int NPB = 32, KT = 84;
    __shared__ __align__(16) float acc[NPB * 2 * KT];   // 21.5 KB (dual copies)
    int tid = threadIdx.x, lane = tid & 63, wv = tid >> 6;
    int n0 = blockIdx.x * NPB;
    for (int k = tid; k < NPB * 2 * KT; k += 256) acc[k] = 0.0f;
    __syncthreads();

    int d = lane >> 5, hl = lane & 31;
    int c = hl / 3, i = hl - c * 3;
    bool act = (hl < 24);
    int cc = act ? c : 0;
    int coff = (c & 1) + 3 * ((c >> 1) & 1) + 9 * (c >> 2);   // corner offset

    for (int g2 = 0; g2 < 8; g2++) {
        int g = wv * 8 + g2;
        int n = n0 + g;
        if (n >= N) continue;
        if (lane < 3) acc[(g * 2) * KT + 81 + lane] = x[(size_t)n * 3 + lane];  // root
        int rs = row_ptr[n], re = row_ptr[n + 1];
        int npairs = (re - rs + 1) >> 1;
        float* accd = &acc[(g * 2 + d) * KT];
        for (int pb = 0; pb < npairs; pb += 4) {
            int metas[4]; float ws_[4], xs_[4];
#pragma unroll
            for (int j = 0; j < 4; j++) {            // clamp invalid -> rs (valid, w=0)
                int ej = rs + (pb + j) * 2 + d;
                bool v = (pb + j < npairs) && (ej < re);
                int ec = v ? ej : rs;
                metas[j] = s_meta[ec];
                float wv_ = s_w[(size_t)ec * 8 + cc];
                ws_[j] = v ? wv_ : 0.0f;
            }
#pragma unroll
            for (int j = 0; j < 4; j++)
                xs_[j] = x[(size_t)(metas[j] & 0xFFFFFF) * 3 + i];
#pragma unroll
            for (int j = 0; j < 4; j++) {
                int kidx = ((metas[j] >> 24) & 0xF) + coff;
                if (act) accd[kidx * 3 + i] += ws_[j] * xs_[j];
            }
        }
    }
    __syncthreads();

    int o = lane;
    float wreg[KT];
#pragma unroll
    for (int k = 0; k < KT; k++)
        wreg[k] = (k < 81) ? W0[k * 64 + o] : Wr[(k - 81) * 64 + o];
    float bv = bias[o];
    for (int g = wv; g < NPB; g += 4) {
        int n = n0 + g;
        if (n >= N) break;
        float s = bv;
#pragma unroll
        for (int k4 = 0; k4 < KT; k4 += 4) {
            floatx4 a0 = *(const floatx4*)&acc[(g * 2) * KT + k4];
            floatx4 a1 = *(const floatx4*)&acc[(g * 2 + 1) * KT + k4];
            s += (a0.x + a1.x) * wreg[k4] + (a0.y + a1.y) * wreg[k4 + 1]
               + (a0.z + a1.z) * wreg[k4 + 2] + (a0.w + a1.w) * wreg[k4 + 3];
        }
        h_out[(size_t)n * 64 + o] = fmaxf(s, 0.0f);
    }
}

// ---------------- 64-ch layers: forced-scalar Phase A + split-K Phase B ----------
__global__ __launch_bounds__(512) void layer64_kernel(
    const float* __restrict__ h_in, const unsigned short* __restrict__ wb,
    const float* __restrict__ bias, const int* __restrict__ row_ptr,
    const int* __restrict__ s_meta, const float* __restrict__ s_w,
    float* __restrict__ h_out, int N) {
    constexpr int NPB = 8;
    constexpr int STR = 1808;            // shorts; dword-stride 904 = even bank spread
    __shared__ __align__(16) unsigned short accb[NPB * STR];   // 28,928 B
    int tid = threadIdx.x, lane = tid & 63;
    int wvu = __builtin_amdgcn_readfirstlane(tid >> 6);   // uniform wave id 0..7
    int n0 = blockIdx.x * NPB;

#define EDGE_FMA(EIDX, XJ) do { \
    const float* wp = s_w + (size_t)(EIDX) * 8; \
    float w0 = wp[0], w1 = wp[1], w2 = wp[2], w3 = wp[3]; \
    float w4 = wp[4], w5 = wp[5], w6 = wp[6], w7 = wp[7]; \
    float xj = (XJ); \
    switch (bases) { \
    case 0:  acc[0]+=w0*xj;  acc[1]+=w1*xj;  acc[3]+=w2*xj;  acc[4]+=w3*xj; \
             acc[9]+=w4*xj;  acc[10]+=w5*xj; acc[12]+=w6*xj; acc[13]+=w7*xj; break; \
    case 1:  acc[1]+=w0*xj;  acc[2]+=w1*xj;  acc[4]+=w2*xj;  acc[5]+=w3*xj; \
             acc[10]+=w4*xj; acc[11]+=w5*xj; acc[13]+=w6*xj; acc[14]+=w7*xj; break; \
    case 3:  acc[3]+=w0*xj;  acc[4]+=w1*xj;  acc[6]+=w2*xj;  acc[7]+=w3*xj; \
             acc[12]+=w4*xj; acc[13]+=w5*xj; acc[15]+=w6*xj; acc[16]+=w7*xj; break; \
    case 4:  acc[4]+=w0*xj;  acc[5]+=w1*xj;  acc[7]+=w2*xj;  acc[8]+=w3*xj; \
             acc[13]+=w4*xj; acc[14]+=w5*xj; acc[16]+=w6*xj; acc[17]+=w7*xj; break; \
    case 9:  acc[9]+=w0*xj;  acc[10]+=w1*xj; acc[12]+=w2*xj; acc[13]+=w3*xj; \
             acc[18]+=w4*xj; acc[19]+=w5*xj; acc[21]+=w6*xj; acc[22]+=w7*xj; break; \
    case 10: acc[10]+=w0*xj; acc[11]+=w1*xj; acc[13]+=w2*xj; acc[14]+=w3*xj; \
             acc[19]+=w4*xj; acc[20]+=w5*xj; acc[22]+=w6*xj; acc[23]+=w7*xj; break; \
    case 12: acc[12]+=w0*xj; acc[13]+=w1*xj; acc[15]+=w2*xj; acc[16]+=w3*xj; \
             acc[21]+=w4*xj; acc[22]+=w5*xj; acc[24]+=w6*xj; acc[25]+=w7*xj; break; \
    default: acc[13]+=w0*xj; acc[14]+=w1*xj; acc[16]+=w2*xj; acc[17]+=w3*xj; \
             acc[22]+=w4*xj; acc[23]+=w5*xj; acc[25]+=w6*xj; acc[26]+=w7*xj; break; } \
} while (0)

// Forced-scalar batch: ONE coalesced lane-load of SZ metas, v_readlane ->
// SGPR src/base per edge; gathers saddr-form; weight loads s_load_dwordx8.
#define BATCH(SZ) do { \
    int mv = s_meta[e + (lane % SZ)]; \
    int srcs[SZ], bss[SZ]; \
    _Pragma("unroll") for (int j = 0; j < SZ; j++) { \
        int mj = __builtin_amdgcn_readlane(mv, j); \
        srcs[j] = mj & 0xFFFFFF; \
        bss[j] = (mj >> 24) & 0xF; \
    } \
    float xjs[SZ]; \
    _Pragma("unroll") for (int j = 0; j < SZ; j++) \
        xjs[j] = h_in[(size_t)srcs[j] * 64 + lane]; \
    _Pragma("unroll") for (int j = 0; j < SZ; j++) { \
        int bases = bss[j]; \
        EDGE_FMA(e + j, xjs[j]); \
    } \
    e += SZ; \
} while (0)

    // Phase A: wave wvu owns node row wvu. lane = channel. e-chain is SGPR.
    {
        int r = wvu;
        int n = n0 + r;
        unsigned short* arowb = &accb[r * STR];
        if (n >= N) {   // tail hygiene: zero the row so MFMA sees no stale LDS
            for (int k = lane; k < 1792; k += 64) arowb[k] = 0;
        } else {
            float acc[27];
#pragma unroll
            for (int m = 0; m < 27; m++) acc[m] = 0.0f;
            int rs = __builtin_amdgcn_readfirstlane(row_ptr[n]);
            int re = __builtin_amdgcn_readfirstlane(row_ptr[n + 1]);
            int e = rs;
            while (e + 16 <= re) BATCH(16);
            if (e + 8 <= re) BATCH(8);
            if (e + 4 <= re) BATCH(4);
            for (; e < re; e++) {                     // <=3 remainder
                int meta = __builtin_amdgcn_readfirstlane(s_meta[e]);
                int srcr = meta & 0xFFFFFF;
                float xjr = h_in[(size_t)srcr * 64 + lane];
                int bases = (meta >> 24) & 0xF;
                EDGE_FMA(e, xjr);
            }
#pragma unroll
            for (int m = 0; m < 27; m++)
                arowb[m * 64 + lane] = (unsigned short)f2bf(acc[m]);
            arowb[1728 + lane] = (unsigned short)f2bf(h_in[(size_t)n * 64 + lane]);
        }
    }
#undef BATCH
#undef EDGE_FMA
    __syncthreads();

    // Phase B (R12-proven): all 8 waves, 2-way split-K (broadcast A reads).
    {
        int t = wvu & 3;
        int hf = wvu >> 2;
        const unsigned short* ap = accb + (lane & 7) * STR + ((lane >> 4) * 8);
        floatx4 facc = {0.0f, 0.0f, 0.0f, 0.0f};
        const unsigned short* wbp = wb + ((size_t)(t * 56) * 64 + lane) * 8;
#pragma unroll
        for (int ci = 0; ci < 28; ci++) {
            int c = hf * 28 + ci;
            short8 af = *(const short8*)(ap + c * 32);
            short8 bfr = *(const short8*)(wbp + (size_t)c * 64 * 8);
            facc = __builtin_amdgcn_mfma_f32_16x16x32_bf16(af, bfr, facc, 0, 0, 0);
        }
        __syncthreads();               // all MFMA reads of accb complete
        float* pf = (float*)accb;      // 8 waves x 256 floats = 8KB (fits)
#pragma unroll
        for (int r = 0; r < 4; r++) pf[wvu * 256 + r * 64 + lane] = facc[r];
        __syncthreads();
        if (wvu < 4) {
            int o = t * 16 + (lane & 15);
            float bv = bias[o];
#pragma unroll
            for (int r = 0; r < 4; r++) {
                int m = (lane >> 4) * 4 + r;
                if (m < 8) {
                    int n = n0 + m;
                    if (n < N) {
                        float s = pf[t * 256 + r * 64 + lane]
                                + pf[(t + 4) * 256 + r * 64 + lane];
                        h_out[(size_t)n * 64 + o] = fmaxf(s + bv, 0.0f);
                    }
                }
            }
        }
    }
}

extern "C" void kernel_launch(void* const* d_in, const int* in_sizes, int n_in,
                              void* d_out, int out_size, void* d_ws, size_t ws_size,
                              hipStream_t stream) {
    (void)n_in; (void)out_size; (void)ws_size;
    const float* x    = (const float*)d_in[0];
    const int*   ei   = (const int*)d_in[1];
    const float* attr = (const float*)d_in[2];
    const float* W0 = (const float*)d_in[3];
    const float* R0 = (const float*)d_in[4];
    const float* B0 = (const float*)d_in[5];
    const float* W1 = (const float*)d_in[6];
    const float* R1 = (const float*)d_in[7];
    const float* B1 = (const float*)d_in[8];
    const float* W2 = (const float*)d_in[9];
    const float* R2 = (const float*)d_in[10];
    const float* B2 = (const float*)d_in[11];
    const int N = in_sizes[0] / 3;
    const int E = in_sizes[1] / 2;

    char* ws = (char*)d_ws;
    size_t off = 0;
    auto alloc = [&](size_t bytes) {
        size_t cur = off;
        off = (off + bytes + 255) & ~(size_t)255;
        return cur;
    };
    int* row_ptr = (int*)(ws + alloc((size_t)(N + 1) * 4));
    int* count   = (int*)(ws + alloc((size_t)N * 4));
    int* cursor  = (int*)(ws + alloc((size_t)N * 4));
    int* bsum    = (int*)(ws + alloc(64 * 4));
    int* boff    = (int*)(ws + alloc(64 * 4));
    int* tot     = (int*)(ws + alloc(4));
    int* s_meta  = (int*)(ws + alloc((size_t)E * 4));
    float* s_w   = (float*)(ws + alloc((size_t)E * 8 * 4));
    float* h_a   = (float*)(ws + alloc((size_t)N * 64 * 4));
    float* h_b   = (float*)(ws + alloc((size_t)N * 64 * 4));
    unsigned short* wb1 = (unsigned short*)(ws + alloc((size_t)4 * 56 * 64 * 8 * 2));
    unsigned short* wb2 = (unsigned short*)(ws + alloc((size_t)4 * 56 * 64 * 8 * 2));

    int nb = (N + 1023) / 1024;   // 49 <= 64

    hipMemsetAsync(count, 0, (size_t)N * 4, stream);
    count_kernel<<<(E + 255) / 256, 256, 0, stream>>>(ei, count, E);
    scan_tile_kernel<<<nb, 1024, 0, stream>>>(count, row_ptr, bsum, N);
    scan_bsum_kernel<<<1, 64, 0, stream>>>(bsum, boff, tot, nb);
    scan_add_kernel<<<nb, 1024, 0, stream>>>(row_ptr, boff, tot, cursor, N);
    basis_sort_kernel<<<(E + 255) / 256, 256, 0, stream>>>(ei, attr, count, cursor,
                                                           s_meta, s_w, E);
    build_wb2<<<(2 * 4 * 56 * 64 + 255) / 256, 256, 0, stream>>>(W1, R1, wb1,
                                                                 W2, R2, wb2);

    layer0_kernel<<<(N + 31) / 32, 256, 0, stream>>>(x, W0, R0, B0, row_ptr,
                                                     s_meta, s_w, h_a, N);
    layer64_kernel<<<(N + 7) / 8, 512, 0, stream>>>(h_a, wb1, B1, row_ptr,
                                                    s_meta, s_w, h_b, N);
    layer64_kernel<<<(N + 7) / 8, 512, 0, stream>>>(h_b, wb2, B2, row_ptr,
                                                    s_meta, s_w, (float*)d_out, N);
}

// Round 15
// 662.676 us; speedup vs baseline: 1.0093x; 1.0093x over previous
//
#include <hip/hip_runtime.h>
#include <cstdint>

// SplineConv MeshEncoder: 3 layers, K=3 DIM=3 M=27, dims 3->64->64->64.
// R15 = R14 with layer64 block HALVED: 256 thr / 4 waves / NPB=4 / 14.5KB LDS.
// Rationale: achieved occupancy stuck at 42% (13 waves/CU) while static
// limits allow 32 — the 512-thr barrier block was the residency quantum
// (4/CU by thread count, wall = max of 8 node degrees). 8 independent 4-wave
// blocks/CU -> more progress streams, less barrier imbalance. Phase B back to
// full-K per wave (split-K proven neutral), A-rows lane&3-dup (broadcast).

typedef __attribute__((ext_vector_type(8))) short short8;
typedef __attribute__((ext_vector_type(4))) float floatx4;

__device__ inline short f2bf(float f) {
    union { float f; unsigned u; } x; x.f = f;
    unsigned r = x.u + 0x7FFF + ((x.u >> 16) & 1);   // round-to-nearest-even
    return (short)(r >> 16);
}

// ---------------- preprocessing (R10-proven) ----------------

__global__ void count_kernel(const int* __restrict__ ei, int* __restrict__ count, int E) {
    int e = blockIdx.x * blockDim.x + threadIdx.x;
    if (e < E) atomicAdd(&count[ei[E + e]], 1);
}

__global__ __launch_bounds__(1024) void scan_tile_kernel(const int* __restrict__ count,
                                                         int* __restrict__ row_ptr,
                                                         int* __restrict__ bsum, int N) {
    __shared__ int wsum[16];
    int tid = threadIdx.x, lane = tid & 63, wid = tid >> 6;
    int i = blockIdx.x * 1024 + tid;
    int v = (i < N) ? count[i] : 0;
    int incl = v;
#pragma unroll
    for (int off = 1; off < 64; off <<= 1) {
        int t = __shfl_up(incl, off, 64);
        if (lane >= off) incl += t;
    }
    if (lane == 63) wsum[wid] = incl;
    __syncthreads();
    if (tid < 16) {
        int w = wsum[tid];
#pragma unroll
        for (int off = 1; off < 16; off <<= 1) {
            int t = __shfl_up(w, off, 16);
            if ((tid & 15) >= off) w += t;
        }
        wsum[tid] = w;
    }
    __syncthreads();
    int waveoff = (wid > 0) ? wsum[wid - 1] : 0;
    if (i < N) row_ptr[i] = waveoff + incl - v;
    if (tid == 1023) bsum[blockIdx.x] = waveoff + incl;
}

__global__ __launch_bounds__(64) void scan_bsum_kernel(const int* __restrict__ bsum,
                                                       int* __restrict__ boff,
                                                       int* __restrict__ tot, int nb) {
    int tid = threadIdx.x;
    int v = (tid < nb) ? bsum[tid] : 0;
    int incl = v;
#pragma unroll
    for (int off = 1; off < 64; off <<= 1) {
        int t = __shfl_up(incl, off, 64);
        if (tid >= off) incl += t;
    }
    boff[tid] = incl - v;
    if (tid == 63) tot[0] = incl;
}

__global__ __launch_bounds__(1024) void scan_add_kernel(int* __restrict__ row_ptr,
                                                        const int* __restrict__ boff,
                                                        const int* __restrict__ tot,
                                                        int* __restrict__ cursor, int N) {
    int i = blockIdx.x * 1024 + threadIdx.x;
    if (i < N) {
        int r = row_ptr[i] + boff[blockIdx.x];
        row_ptr[i] = r;
        cursor[i] = r;
    }
    if (i == 0) row_ptr[N] = tot[0];
}

// Per edge: meta = src | base<<24, weights pre-scaled by 1/deg, scattered to
// dst-sorted position (two float4 stores). kidx = base + {0,1,3,4,9,10,12,13}[c].
__global__ void basis_sort_kernel(const int* __restrict__ ei, const float* __restrict__ attr,
                                  const int* __restrict__ count, int* __restrict__ cursor,
                                  int* __restrict__ s_meta, float* __restrict__ s_w, int E) {
    int e = blockIdx.x * blockDim.x + threadIdx.x;
    if (e >= E) return;
    int src = ei[e];
    int dst = ei[E + e];
    float f[3]; int i0[3];
#pragma unroll
    for (int d = 0; d < 3; d++) {
        float pos = attr[e * 3 + d] * 2.0f;          // K-1 = 2
        float fl = floorf(pos);
        fl = fminf(fmaxf(fl, 0.0f), 1.0f);           // clip to [0, K-2]
        i0[d] = (int)fl;
        f[d] = pos - fl;
    }
    int base = i0[0] + 3 * i0[1] + 9 * i0[2];        // in {0,1,3,4,9,10,12,13}
    float invd = 1.0f / fmaxf((float)count[dst], 1.0f);
    int p = atomicAdd(&cursor[dst], 1);
    s_meta[p] = src | (base << 24);
    float w[8];
#pragma unroll
    for (int c = 0; c < 8; c++) {
        float ww = 1.0f;
#pragma unroll
        for (int d = 0; d < 3; d++) {
            int off = (c >> d) & 1;
            ww *= off ? f[d] : (1.0f - f[d]);
        }
        w[c] = ww * invd;
    }
    floatx4 w03 = {w[0], w[1], w[2], w[3]};
    floatx4 w47 = {w[4], w[5], w[6], w[7]};
    *(floatx4*)(s_w + (size_t)p * 8) = w03;
    *(floatx4*)(s_w + (size_t)p * 8 + 4) = w47;
}

// Pre-swizzle [W(1728,64); Wr(64,64)] into bf16 MFMA B-frag order (R1-proven).
__global__ void build_wb2(const float* __restrict__ Wa, const float* __restrict__ Ra,
                          unsigned short* __restrict__ wba,
                          const float* __restrict__ Wb, const float* __restrict__ Rb,
                          unsigned short* __restrict__ wbb) {
    int idx0 = blockIdx.x * blockDim.x + threadIdx.x;   // [0, 2*4*56*64)
    int half = idx0 / (4 * 56 * 64);
    if (half >= 2) return;
    int idx = idx0 - half * (4 * 56 * 64);
    const float* W = half ? Wb : Wa;
    const float* Wr = half ? Rb : Ra;
    unsigned short* wb = half ? wbb : wba;
    int l = idx & 63;
    int c = (idx >> 6) % 56;
    int t = idx / (56 * 64);
    int q = l >> 4, o = t * 16 + (l & 15);
    short8 out;
#pragma unroll
    for (int j = 0; j < 8; j++) {
        int k = c * 32 + q * 8 + j;
        float v = (k < 1728) ? W[(size_t)k * 64 + o] : Wr[(size_t)(k - 1728) * 64 + o];
        out[j] = f2bf(v);
    }
    *(short8*)(wb + (size_t)idx * 8) = out;
}

// ---------------- layer 0 (CIN=3): dual-edge Phase A (R13-proven) ----------------
__global__ __launch_bounds__(256) void layer0_kernel(
    const float* __restrict__ x, const float* __restrict__ W0,
    const float* __restrict__ Wr, const float* __restrict__ bias,
    const int* __restrict__ row_ptr, const int* __restrict__ s_meta,
    const float* __restrict__ s_w, float* __restrict__ h_out, int N) {
    constexpr int NPB = 32, KT = 84;
    __shared__ __align__(16) float acc[NPB * 2 * KT];   // 21.5 KB (dual copies)
    int tid = threadIdx.x, lane = tid & 63, wv = tid >> 6;
    int n0 = blockIdx.x * NPB;
    for (int k = tid; k < NPB * 2 * KT; k += 256) acc[k] = 0.0f;
    __syncthreads();

    int d = lane >> 5, hl = lane & 31;
    int c = hl / 3, i = hl - c * 3;
    bool act = (hl < 24);
    int cc = act ? c : 0;
    int coff = (c & 1) + 3 * ((c >> 1) & 1) + 9 * (c >> 2);   // corner offset

    for (int g2 = 0; g2 < 8; g2++) {
        int g = wv * 8 + g2;
        int n = n0 + g;
        if (n >= N) continue;
        if (lane < 3) acc[(g * 2) * KT + 81 + lane] = x[(size_t)n * 3 + lane];  // root
        int rs = row_ptr[n], re = row_ptr[n + 1];
        int npairs = (re - rs + 1) >> 1;
        float* accd = &acc[(g * 2 + d) * KT];
        for (int pb = 0; pb < npairs; pb += 4) {
            int metas[4]; float ws_[4], xs_[4];
#pragma unroll
            for (int j = 0; j < 4; j++) {            // clamp invalid -> rs (valid, w=0)
                int ej = rs + (pb + j) * 2 + d;
                bool v = (pb + j < npairs) && (ej < re);
                int ec = v ? ej : rs;
                metas[j] = s_meta[ec];
                float wv_ = s_w[(size_t)ec * 8 + cc];
                ws_[j] = v ? wv_ : 0.0f;
            }
#pragma unroll
            for (int j = 0; j < 4; j++)
                xs_[j] = x[(size_t)(metas[j] & 0xFFFFFF) * 3 + i];
#pragma unroll
            for (int j = 0; j < 4; j++) {
                int kidx = ((metas[j] >> 24) & 0xF) + coff;
                if (act) accd[kidx * 3 + i] += ws_[j] * xs_[j];
            }
        }
    }
    __syncthreads();

    int o = lane;
    float wreg[KT];
#pragma unroll
    for (int k = 0; k < KT; k++)
        wreg[k] = (k < 81) ? W0[k * 64 + o] : Wr[(k - 81) * 64 + o];
    float bv = bias[o];
    for (int g = wv; g < NPB; g += 4) {
        int n = n0 + g;
        if (n >= N) break;
        float s = bv;
#pragma unroll
        for (int k4 = 0; k4 < KT; k4 += 4) {
            floatx4 a0 = *(const floatx4*)&acc[(g * 2) * KT + k4];
            floatx4 a1 = *(const floatx4*)&acc[(g * 2 + 1) * KT + k4];
            s += (a0.x + a1.x) * wreg[k4] + (a0.y + a1.y) * wreg[k4 + 1]
               + (a0.z + a1.z) * wreg[k4 + 2] + (a0.w + a1.w) * wreg[k4 + 3];
        }
        h_out[(size_t)n * 64 + o] = fmaxf(s, 0.0f);
    }
}

// ---------------- 64-ch layers: 256 thr / 4 waves / NPB=4 ----------------
__global__ __launch_bounds__(256) void layer64_kernel(
    const float* __restrict__ h_in, const unsigned short* __restrict__ wb,
    const float* __restrict__ bias, const int* __restrict__ row_ptr,
    const int* __restrict__ s_meta, const float* __restrict__ s_w,
    float* __restrict__ h_out, int N) {
    constexpr int NPB = 4;
    constexpr int STR = 1808;            // shorts; dword-stride 904 = even bank spread
    __shared__ __align__(16) unsigned short accb[NPB * STR];   // 14,464 B -> 8 blk/CU
    int tid = threadIdx.x, lane = tid & 63;
    int wvu = __builtin_amdgcn_readfirstlane(tid >> 6);   // uniform wave id 0..3
    int n0 = blockIdx.x * NPB;

#define EDGE_FMA(EIDX, XJ) do { \
    const float* wp = s_w + (size_t)(EIDX) * 8; \
    float w0 = wp[0], w1 = wp[1], w2 = wp[2], w3 = wp[3]; \
    float w4 = wp[4], w5 = wp[5], w6 = wp[6], w7 = wp[7]; \
    float xj = (XJ); \
    switch (bases) { \
    case 0:  acc[0]+=w0*xj;  acc[1]+=w1*xj;  acc[3]+=w2*xj;  acc[4]+=w3*xj; \
             acc[9]+=w4*xj;  acc[10]+=w5*xj; acc[12]+=w6*xj; acc[13]+=w7*xj; break; \
    case 1:  acc[1]+=w0*xj;  acc[2]+=w1*xj;  acc[4]+=w2*xj;  acc[5]+=w3*xj; \
             acc[10]+=w4*xj; acc[11]+=w5*xj; acc[13]+=w6*xj; acc[14]+=w7*xj; break; \
    case 3:  acc[3]+=w0*xj;  acc[4]+=w1*xj;  acc[6]+=w2*xj;  acc[7]+=w3*xj; \
             acc[12]+=w4*xj; acc[13]+=w5*xj; acc[15]+=w6*xj; acc[16]+=w7*xj; break; \
    case 4:  acc[4]+=w0*xj;  acc[5]+=w1*xj;  acc[7]+=w2*xj;  acc[8]+=w3*xj; \
             acc[13]+=w4*xj; acc[14]+=w5*xj; acc[16]+=w6*xj; acc[17]+=w7*xj; break; \
    case 9:  acc[9]+=w0*xj;  acc[10]+=w1*xj; acc[12]+=w2*xj; acc[13]+=w3*xj; \
             acc[18]+=w4*xj; acc[19]+=w5*xj; acc[21]+=w6*xj; acc[22]+=w7*xj; break; \
    case 10: acc[10]+=w0*xj; acc[11]+=w1*xj; acc[13]+=w2*xj; acc[14]+=w3*xj; \
             acc[19]+=w4*xj; acc[20]+=w5*xj; acc[22]+=w6*xj; acc[23]+=w7*xj; break; \
    case 12: acc[12]+=w0*xj; acc[13]+=w1*xj; acc[15]+=w2*xj; acc[16]+=w3*xj; \
             acc[21]+=w4*xj; acc[22]+=w5*xj; acc[24]+=w6*xj; acc[25]+=w7*xj; break; \
    default: acc[13]+=w0*xj; acc[14]+=w1*xj; acc[16]+=w2*xj; acc[17]+=w3*xj; \
             acc[22]+=w4*xj; acc[23]+=w5*xj; acc[25]+=w6*xj; acc[26]+=w7*xj; break; } \
} while (0)

// Forced-scalar batch (R14-proven): ONE coalesced lane-load of SZ metas,
// v_readlane -> SGPR src/base per edge.
#define BATCH(SZ) do { \
    int mv = s_meta[e + (lane % SZ)]; \
    int srcs[SZ], bss[SZ]; \
    _Pragma("unroll") for (int j = 0; j < SZ; j++) { \
        int mj = __builtin_amdgcn_readlane(mv, j); \
        srcs[j] = mj & 0xFFFFFF; \
        bss[j] = (mj >> 24) & 0xF; \
    } \
    float xjs[SZ]; \
    _Pragma("unroll") for (int j = 0; j < SZ; j++) \
        xjs[j] = h_in[(size_t)srcs[j] * 64 + lane]; \
    _Pragma("unroll") for (int j = 0; j < SZ; j++) { \
        int bases = bss[j]; \
        EDGE_FMA(e + j, xjs[j]); \
    } \
    e += SZ; \
} while (0)

    // Phase A: wave wvu owns node row wvu (0..3). lane = channel.
    {
        int r = wvu;
        int n = n0 + r;
        unsigned short* arowb = &accb[r * STR];
        if (n >= N) {   // tail hygiene: zero the row so MFMA sees no stale LDS
            for (int k = lane; k < 1792; k += 64) arowb[k] = 0;
        } else {
            float acc[27];
#pragma unroll
            for (int m = 0; m < 27; m++) acc[m] = 0.0f;
            int rs = __builtin_amdgcn_readfirstlane(row_ptr[n]);
            int re = __builtin_amdgcn_readfirstlane(row_ptr[n + 1]);
            int e = rs;
            while (e + 16 <= re) BATCH(16);
            if (e + 8 <= re) BATCH(8);
            if (e + 4 <= re) BATCH(4);
            for (; e < re; e++) {                     // <=3 remainder
                int meta = __builtin_amdgcn_readfirstlane(s_meta[e]);
                int srcr = meta & 0xFFFFFF;
                float xjr = h_in[(size_t)srcr * 64 + lane];
                int bases = (meta >> 24) & 0xF;
                EDGE_FMA(e, xjr);
            }
#pragma unroll
            for (int m = 0; m < 27; m++)
                arowb[m * 64 + lane] = (unsigned short)f2bf(acc[m]);
            arowb[1728 + lane] = (unsigned short)f2bf(h_in[(size_t)n * 64 + lane]);
        }
    }
#undef BATCH
#undef EDGE_FMA
    __syncthreads();

    // Phase B: wave t -> out-tile t (16 chans), full K=56. A rows lane&3-dup
    // (4 real nodes; broadcast LDS reads, conflict-free). Store rows m<4.
    {
        int t = wvu;
        const unsigned short* ap = accb + (lane & 3) * STR + ((lane >> 4) * 8);
        floatx4 facc = {0.0f, 0.0f, 0.0f, 0.0f};
        const unsigned short* wbp = wb + ((size_t)(t * 56) * 64 + lane) * 8;
#pragma unroll 4
        for (int c = 0; c < 56; c++) {
            short8 af = *(const short8*)(ap + c * 32);
            short8 bfr = *(const short8*)(wbp + (size_t)c * 64 * 8);
            facc = __builtin_amdgcn_mfma_f32_16x16x32_bf16(af, bfr, facc, 0, 0, 0);
        }
        int o = t * 16 + (lane & 15);
        float bv = bias[o];
#pragma unroll
        for (int r = 0; r < 4; r++) {
            int m = (lane >> 4) * 4 + r;
            if (m < 4) {
                int n = n0 + m;
                if (n < N) h_out[(size_t)n * 64 + o] = fmaxf(facc[r] + bv, 0.0f);
            }
        }
    }
}

extern "C" void kernel_launch(void* const* d_in, const int* in_sizes, int n_in,
                              void* d_out, int out_size, void* d_ws, size_t ws_size,
                              hipStream_t stream) {
    (void)n_in; (void)out_size; (void)ws_size;
    const float* x    = (const float*)d_in[0];
    const int*   ei   = (const int*)d_in[1];
    const float* attr = (const float*)d_in[2];
    const float* W0 = (const float*)d_in[3];
    const float* R0 = (const float*)d_in[4];
    const float* B0 = (const float*)d_in[5];
    const float* W1 = (const float*)d_in[6];
    const float* R1 = (const float*)d_in[7];
    const float* B1 = (const float*)d_in[8];
    const float* W2 = (const float*)d_in[9];
    const float* R2 = (const float*)d_in[10];
    const float* B2 = (const float*)d_in[11];
    const int N = in_sizes[0] / 3;
    const int E = in_sizes[1] / 2;

    char* ws = (char*)d_ws;
    size_t off = 0;
    auto alloc = [&](size_t bytes) {
        size_t cur = off;
        off = (off + bytes + 255) & ~(size_t)255;
        return cur;
    };
    int* row_ptr = (int*)(ws + alloc((size_t)(N + 1) * 4));
    int* count   = (int*)(ws + alloc((size_t)N * 4));
    int* cursor  = (int*)(ws + alloc((size_t)N * 4));
    int* bsum    = (int*)(ws + alloc(64 * 4));
    int* boff    = (int*)(ws + alloc(64 * 4));
    int* tot     = (int*)(ws + alloc(4));
    int* s_meta  = (int*)(ws + alloc((size_t)E * 4));
    float* s_w   = (float*)(ws + alloc((size_t)E * 8 * 4));
    float* h_a   = (float*)(ws + alloc((size_t)N * 64 * 4));
    float* h_b   = (float*)(ws + alloc((size_t)N * 64 * 4));
    unsigned short* wb1 = (unsigned short*)(ws + alloc((size_t)4 * 56 * 64 * 8 * 2));
    unsigned short* wb2 = (unsigned short*)(ws + alloc((size_t)4 * 56 * 64 * 8 * 2));

    int nb = (N + 1023) / 1024;   // 49 <= 64

    hipMemsetAsync(count, 0, (size_t)N * 4, stream);
    count_kernel<<<(E + 255) / 256, 256, 0, stream>>>(ei, count, E);
    scan_tile_kernel<<<nb, 1024, 0, stream>>>(count, row_ptr, bsum, N);
    scan_bsum_kernel<<<1, 64, 0, stream>>>(bsum, boff, tot, nb);
    scan_add_kernel<<<nb, 1024, 0, stream>>>(row_ptr, boff, tot, cursor, N);
    basis_sort_kernel<<<(E + 255) / 256, 256, 0, stream>>>(ei, attr, count, cursor,
                                                           s_meta, s_w, E);
    build_wb2<<<(2 * 4 * 56 * 64 + 255) / 256, 256, 0, stream>>>(W1, R1, wb1,
                                                                 W2, R2, wb2);

    layer0_kernel<<<(N + 31) / 32, 256, 0, stream>>>(x, W0, R0, B0, row_ptr,
                                                     s_meta, s_w, h_a, N);
    layer64_kernel<<<(N + 3) / 4, 256, 0, stream>>>(h_a, wb1, B1, row_ptr,
                                                    s_meta, s_w, h_b, N);
    layer64_kernel<<<(N + 3) / 4, 256, 0, stream>>>(h_b, wb2, B2, row_ptr,
                                                    s_meta, s_w, (float*)d_out, N);
}